// Round 15
// baseline (939.905 us; speedup 1.0000x reference)
//
#include <hip/hip_runtime.h>
#include <math.h>

#define NN 16384
#define KK 16
#define RPW 4                       // rows per scan wave
#define SW 4                        // scan waves per block
#define RPB (SW * RPW)              // 16 rows per block
#define CAP 128                     // per-row candidate buffer (u64 keys)
#define NB 1024                     // x-sort buckets
#define NT 64                       // tiles of 256 sorted points

typedef float f32x4 __attribute__((ext_vector_type(4)));
typedef unsigned long long u64;

// ---- d_ws layout (bytes): pts | perm | hist | cur | tileMM  (~337 KB) ----
#define WS_PTS   0
#define WS_PERM  (NN * 16)
#define WS_HIST  (WS_PERM + NN * 4)
#define WS_CUR   (WS_HIST + NB * 4)
#define WS_TMM   (WS_CUR + NB * 4)

// ---------------- sort pipeline (4 tiny kernels) ----------------
__global__ void zero_hist(int* __restrict__ hist) { hist[threadIdx.x] = 0; }

__device__ __forceinline__ int xbucket(float x) {
    int b = (int)((x + 6.0f) * (NB / 12.0f));
    return b < 0 ? 0 : (b > NB - 1 ? NB - 1 : b);
}

__global__ void hist_kernel(const float* __restrict__ nodes, int* __restrict__ hist) {
    const int i = blockIdx.x * 256 + threadIdx.x;
    atomicAdd(&hist[xbucket(nodes[3 * i])], 1);
}

__global__ void scan_kernel(const int* __restrict__ hist, int* __restrict__ cur) {
    __shared__ int s[NB];
    const int tid = threadIdx.x;
    const int h0 = hist[tid];
    s[tid] = h0; __syncthreads();
    for (int o = 1; o < NB; o <<= 1) {
        const int v = (tid >= o) ? s[tid - o] : 0;
        __syncthreads();
        s[tid] += v;
        __syncthreads();
    }
    cur[tid] = s[tid] - h0;     // exclusive prefix
}

__global__ void scatter_kernel(const float* __restrict__ nodes, int* __restrict__ cur,
                               float4* __restrict__ pts, int* __restrict__ perm) {
#pragma clang fp contract(off)
    const int i = blockIdx.x * 256 + threadIdx.x;
    const float x = nodes[3 * i], y = nodes[3 * i + 1], z = nodes[3 * i + 2];
    const float sq = (x * x + y * y) + z * z;     // reference arithmetic
    const int pos = atomicAdd(&cur[xbucket(x)], 1);
    pts[pos] = make_float4(x, y, z, sq);
    perm[pos] = i;
}

__global__ void bounds_kernel(const float4* __restrict__ pts, float2* __restrict__ tmm) {
    __shared__ float mn[256], mx[256];
    const int tid = threadIdx.x;
    const float x = pts[blockIdx.x * 256 + tid].x;
    mn[tid] = x; mx[tid] = x; __syncthreads();
    for (int o = 128; o >= 1; o >>= 1) {
        if (tid < o) { mn[tid] = fminf(mn[tid], mn[tid + o]); mx[tid] = fmaxf(mx[tid], mx[tid + o]); }
        __syncthreads();
    }
    if (tid == 0) tmm[blockIdx.x] = make_float2(mn[0], mx[0]);
}

// ---------------- verified helpers ----------------
__device__ __forceinline__ float bcastf(float v, int l) {
    return __int_as_float(__builtin_amdgcn_readlane(__float_as_int(v), l));
}
__device__ __forceinline__ bool lexless(float da, int ia, float db, int ib) {
    return (da < db) || ((da == db) && (ia < ib));
}
// r1-r6-verified distributed insert — overflow fallback only (idx-agnostic).
__device__ __forceinline__ void insert_tile(bool rough, float d2, int j,
                                            float& ld, int& li,
                                            float& td, int& ti, float& td2u,
                                            int lane) {
#pragma clang fp contract(off)
    if (!__any(rough)) return;
    float dist = INFINITY;
    if (rough) dist = sqrtf(fmaxf(d2, 0.0f));
    bool done = false;
    while (true) {
        const bool pass = (!done) && rough && lexless(dist, j, td, ti);
        const u64 m = __ballot(pass);
        if (m == 0ull) break;
        const int src = __ffsll(m) - 1;
        const float dc = __shfl(dist, src);
        const int   ic = __shfl(j, src);
        if (lane == src) done = true;
        const bool gt = lexless(dc, ic, ld, li);
        const u64 gm = __ballot(gt);
        const int p = __ffsll(gm) - 1;
        const float pd = __shfl_up(ld, 1);
        const int   pi = __shfl_up(li, 1);
        if (gt) {
            if (lane == p) { ld = dc; li = ic; }
            else           { ld = pd; li = pi; }
        }
        td = __shfl(ld, 16);
        ti = __shfl(li, 16);
        td2u = td * td * 1.000001f;
    }
}

// ---------------- main kernel: 4 scan waves + 1 fill wave ----------------
__global__ __launch_bounds__(320) void knn_main(const float4* __restrict__ pts,
                                                const int* __restrict__ perm,
                                                const float2* __restrict__ tmm_g,
                                                float* __restrict__ out) {
#pragma clang fp contract(off)
    const int lane = threadIdx.x & 63;
    const int wid  = threadIdx.x >> 6;
    const int tid  = threadIdx.x;
    const int rowBase = blockIdx.x * RPB;   // sorted-row base

    __shared__ float2 tmm[NT];
    __shared__ int prow[RPB];               // original row indices
    __shared__ u64 buf[SW][RPW][CAP];
    __shared__ int cnt[SW][RPW];
    __shared__ int nb[RPB][KK];             // original col indices

    if (tid < NT)  tmm[tid]  = tmm_g[tid];
    if (tid < RPB) prow[tid] = perm[rowBase + tid];
    __syncthreads();

    if (wid == SW) {
        // Fill wave: NT-stream zeros for the block's 16 (scattered) rows.
        const f32x4 z4 = {0.f, 0.f, 0.f, 0.f};
        for (int r = 0; r < RPB; ++r) {
            f32x4* ob = (f32x4*)(out + (size_t)prow[r] * NN);
#pragma unroll 8
            for (int k = 0; k < (NN / 4) / 64; ++k)
                __builtin_nontemporal_store(z4, ob + k * 64 + lane);
        }
        asm volatile("s_waitcnt vmcnt(0)" ::: "memory");   // order 1.0s after zeros
    } else {
        const int r0 = rowBase + wid * RPW;
        float xs[RPW], ys[RPW], zs[RPW], ss[RPW];
#pragma unroll
        for (int r = 0; r < RPW; ++r) {
            const float4 p = pts[r0 + r];
            xs[r] = p.x; ys[r] = p.y; zs[r] = p.z; ss[r] = p.w;
        }

        // ===== tau phase: 3 neighboring tiles (768 actual candidates) =====
        int ta = (rowBase >> 8) - 1;
        ta = ta < 0 ? 0 : (ta > NT - 3 ? NT - 3 : ta);
        float rm[RPW];
#pragma unroll
        for (int r = 0; r < RPW; ++r) rm[r] = INFINITY;
        for (int tt = 0; tt < 3; ++tt) {
            const int tb = (ta + tt) * 256;
            const float4 q0 = pts[tb + lane];
            const float4 q1 = pts[tb + 64 + lane];
            const float4 q2 = pts[tb + 128 + lane];
            const float4 q3 = pts[tb + 192 + lane];
#pragma unroll
            for (int r = 0; r < RPW; ++r) {
                const float d0 = (ss[r] + q0.w) - 2.0f * fmaf(zs[r], q0.z, fmaf(ys[r], q0.y, xs[r] * q0.x));
                const float d1 = (ss[r] + q1.w) - 2.0f * fmaf(zs[r], q1.z, fmaf(ys[r], q1.y, xs[r] * q1.x));
                const float d2 = (ss[r] + q2.w) - 2.0f * fmaf(zs[r], q2.z, fmaf(ys[r], q2.y, xs[r] * q2.x));
                const float d3 = (ss[r] + q3.w) - 2.0f * fmaf(zs[r], q3.z, fmaf(ys[r], q3.y, xs[r] * q3.x));
                rm[r] = fminf(rm[r], fminf(fminf(d0, d1), fminf(d2, d3)));
            }
        }
        // r12-verified bitonic sort of 64 lane-mins; tau = 17th (conservative).
        float sv[RPW];
#pragma unroll
        for (int r = 0; r < RPW; ++r) sv[r] = rm[r];
#pragma unroll
        for (int k = 2; k <= 64; k <<= 1) {
#pragma unroll
            for (int j = k >> 1; j >= 1; j >>= 1) {
                const bool keepmin = (((lane & j) == 0) == ((lane & k) == 0));
#pragma unroll
                for (int r = 0; r < RPW; ++r) {
                    const float o = __shfl_xor(sv[r], j);
                    sv[r] = keepmin ? fminf(sv[r], o) : fmaxf(sv[r], o);
                }
            }
        }
        float tau[RPW];
#pragma unroll
        for (int r = 0; r < RPW; ++r)   // *1.000002+eps: sqrt-tie-collapse guard
            tau[r] = fmaxf(bcastf(sv[r], 16), 0.0f) * 1.000002f + 1e-30f;

        if (lane < RPW) cnt[wid][lane] = 0;
        asm volatile("s_waitcnt lgkmcnt(0)" ::: "memory");

        // ===== screen pass: AABB-pruned tiles, verified append body =====
        for (int t = 0; t < NT; ++t) {
            const float2 mm = tmm[t];
            bool kp[RPW]; bool anyk = false;
#pragma unroll
            for (int r = 0; r < RPW; ++r) {
                const float dx = fmaxf(fmaxf(mm.x - xs[r], xs[r] - mm.y), 0.0f);
                // prune slack: fp32 cancellation bound on ref-d2 vs true-d2
                kp[r] = (dx * dx <= tau[r] * 1.00001f + 5e-5f);
                anyk |= kp[r];
            }
            if (!anyk) continue;        // wave-uniform skip
            const int base = t * 256;
            const float4 q0 = pts[base + lane];
            const float4 q1 = pts[base + 64 + lane];
            const float4 q2 = pts[base + 128 + lane];
            const float4 q3 = pts[base + 192 + lane];
#pragma unroll
            for (int r = 0; r < RPW; ++r) {
                if (!kp[r]) continue;
                const float d0 = (ss[r] + q0.w) - 2.0f * fmaf(zs[r], q0.z, fmaf(ys[r], q0.y, xs[r] * q0.x));
                const float d1 = (ss[r] + q1.w) - 2.0f * fmaf(zs[r], q1.z, fmaf(ys[r], q1.y, xs[r] * q1.x));
                const float d2 = (ss[r] + q2.w) - 2.0f * fmaf(zs[r], q2.z, fmaf(ys[r], q2.y, xs[r] * q2.x));
                const float d3 = (ss[r] + q3.w) - 2.0f * fmaf(zs[r], q3.z, fmaf(ys[r], q3.y, xs[r] * q3.x));
                const bool p0 = d0 <= tau[r], p1 = d1 <= tau[r];
                const bool p2 = d2 <= tau[r], p3 = d3 <= tau[r];
                if (p0 | p1 | p2 | p3) {
                    if (p0) { const int o = atomicAdd(&cnt[wid][r], 1);
                              if (o < CAP) buf[wid][r][o] = (((u64)__float_as_uint(fmaxf(d0, 0.f))) << 32) | (unsigned)(base + lane); }
                    if (p1) { const int o = atomicAdd(&cnt[wid][r], 1);
                              if (o < CAP) buf[wid][r][o] = (((u64)__float_as_uint(fmaxf(d1, 0.f))) << 32) | (unsigned)(base + 64 + lane); }
                    if (p2) { const int o = atomicAdd(&cnt[wid][r], 1);
                              if (o < CAP) buf[wid][r][o] = (((u64)__float_as_uint(fmaxf(d2, 0.f))) << 32) | (unsigned)(base + 128 + lane); }
                    if (p3) { const int o = atomicAdd(&cnt[wid][r], 1);
                              if (o < CAP) buf[wid][r][o] = (((u64)__float_as_uint(fmaxf(d3, 0.f))) << 32) | (unsigned)(base + 192 + lane); }
                }
            }
        }
        asm volatile("s_waitcnt lgkmcnt(0)" ::: "memory");

        // ===== select: exact lex-(dist, ORIGINAL idx) rank (r14-verified) =====
#pragma unroll
        for (int r = 0; r < RPW; ++r) {
            const int C = cnt[wid][r];
            const int rowl = wid * RPW + r;
            if (C <= CAP) {                 // C >= 17 guaranteed (tau subset bound)
                for (int e = lane; e < C; e += 64) {
                    const u64 k2 = buf[wid][r][e];
                    const float dd = sqrtf(__uint_as_float((unsigned)(k2 >> 32)));
                    const int oi = perm[(int)(k2 & 0xffffffffu)];   // sorted -> orig
                    buf[wid][r][e] = (((u64)__float_as_uint(dd)) << 32) | (unsigned)oi;
                }
                asm volatile("s_waitcnt lgkmcnt(0) vmcnt(0)" ::: "memory");
                for (int e = lane; e < C; e += 64) {
                    const u64 my = buf[wid][r][e];
                    int rk = 0;
                    for (int c = 0; c < C; ++c)
                        rk += (buf[wid][r][c] < my) ? 1 : 0;   // orig idx unique
                    if (rk >= 1 && rk <= KK)
                        nb[rowl][rk - 1] = (int)(my & 0xffffffffu);  // rank 0 dropped
                }
            } else {
                // Pathological overflow: verified full-scan insert, orig-idx keys.
                float ld = INFINITY; int li = 0x7fffffff;
                float td = INFINITY; int ti = 0x7fffffff; float t2 = INFINITY;
                for (int tt = 0; tt < NN / 64; ++tt) {
                    const int j = tt * 64 + lane;
                    const float4 q = pts[j];
                    const int oi = perm[j];
                    const float dd = (ss[r] + q.w) - 2.0f * fmaf(zs[r], q.z, fmaf(ys[r], q.y, xs[r] * q.x));
                    insert_tile(dd <= t2, dd, oi, ld, li, td, ti, t2, lane);
                }
                if (lane >= 1 && lane <= KK) nb[rowl][lane - 1] = li;
            }
        }
    }

    __syncthreads();

    // Fill wave writes all 256 ones, ordered after its drained zeros
    // (same-wave ordering, r6/r14-verified pattern). Rows/cols are original.
    if (wid == SW) {
#pragma unroll
        for (int m = lane; m < RPB * KK; m += 64) {
            const int r = m >> 4;
            out[(size_t)prow[r] * NN + nb[r][m & 15]] = 1.0f;
        }
    }
}

extern "C" void kernel_launch(void* const* d_in, const int* in_sizes, int n_in,
                              void* d_out, int out_size, void* d_ws, size_t ws_size,
                              hipStream_t stream) {
    const float* nodes = (const float*)d_in[0];
    float* out = (float*)d_out;
    (void)in_sizes; (void)n_in; (void)out_size; (void)ws_size;

    char* ws = (char*)d_ws;
    float4* pts  = (float4*)(ws + WS_PTS);
    int*    perm = (int*)   (ws + WS_PERM);
    int*    hist = (int*)   (ws + WS_HIST);
    int*    cur  = (int*)   (ws + WS_CUR);
    float2* tmm  = (float2*)(ws + WS_TMM);

    hipLaunchKernelGGL(zero_hist,     dim3(1),        dim3(NB),  0, stream, hist);
    hipLaunchKernelGGL(hist_kernel,   dim3(NN / 256), dim3(256), 0, stream, nodes, hist);
    hipLaunchKernelGGL(scan_kernel,   dim3(1),        dim3(NB),  0, stream, hist, cur);
    hipLaunchKernelGGL(scatter_kernel,dim3(NN / 256), dim3(256), 0, stream, nodes, cur, pts, perm);
    hipLaunchKernelGGL(bounds_kernel, dim3(NT),       dim3(256), 0, stream, pts, tmm);
    hipLaunchKernelGGL(knn_main,      dim3(NN / RPB), dim3(320), 0, stream, pts, perm, tmm, out);
}